// Round 10
// baseline (488.022 us; speedup 1.0000x reference)
//
#include <hip/hip_runtime.h>
#include <hip/hip_bf16.h>

#define BN 8
#define HN 128
#define WN 128
#define CN 256
#define DTC 0.2f
#define EPSV 1e-3f
#define NTH 1024

#define SJ 32      // staged channel rows (phys j: cj = c0-8+j)
#define SW 134     // w stride (u16): col0 & col129 zero pads, data at 1..128; rows 4B-aligned
#define HBS 132    // h-buffer row stride (floats): ≡4 mod 32 banks -> pass-5 column reads 2-way (free)

// ---- dtype-generic helpers (compute stays f32) ----
__device__ __forceinline__ float ldf(const float* p)            { return *p; }
__device__ __forceinline__ float ldf(const __hip_bfloat16* p)   { return __bfloat162float(*p); }
__device__ __forceinline__ void stf(float* p, float v)          { *p = v; }
__device__ __forceinline__ void stf(__hip_bfloat16* p, float v) { *p = __float2bfloat16(v); }

// packed bf16 extraction from u32 (exact f32), little-endian: lo = even col
__device__ __forceinline__ float lo16(unsigned u){ return __uint_as_float(u << 16); }
__device__ __forceinline__ float hi16(unsigned u){ return __uint_as_float(u & 0xffff0000u); }

// stage 4 consecutive channels (one vector global load) into 4 LDS channel-rows
__device__ __forceinline__ void stage4(__hip_bfloat16* dp, const __hip_bfloat16* gp) {
    ushort4 v = *reinterpret_cast<const ushort4*>(gp);
    unsigned short* d = reinterpret_cast<unsigned short*>(dp);
    d[0] = v.x; d[SW] = v.y; d[2*SW] = v.z; d[3*SW] = v.w;
}
__device__ __forceinline__ void stage4(__hip_bfloat16* dp, const float* gp) {
    float4 v = *reinterpret_cast<const float4*>(gp);
    dp[0]    = __float2bfloat16(v.x);
    dp[SW]   = __float2bfloat16(v.y);
    dp[2*SW] = __float2bfloat16(v.z);
    dp[3*SW] = __float2bfloat16(v.w);
}

// ---- dtype probe: bf16 exponent band test on raw u32 words ----
__global__ void probe_kernel(const unsigned int* __restrict__ s0w, int* __restrict__ flag) {
    __shared__ int cnt;
    if (threadIdx.x == 0) cnt = 0;
    __syncthreads();
    int local = 0;
    for (int i = threadIdx.x; i < 4096; i += 256) {
        unsigned int e = (s0w[i] >> 7) & 0xFF;
        if (e >= 118 && e <= 130) local++;
    }
    atomicAdd(&cnt, local);
    __syncthreads();
    if (threadIdx.x == 0) *flag = (cnt > 2048) ? 1 : 0;   // 1 = bf16, 0 = f32
}

__device__ __forceinline__ void mkcoef(float gy, float gx, float gg, float g11,
                                       float gl, float gr, float g1u, float g1d, float fsrc,
                                       float& o0, float& oE, float& omx, float& opx,
                                       float& omy, float& opy, float& oS)
{
    // v_rcp_f32 (1 ulp) — tolerance 0.0625; validated r2-r4/r7/r8.
    float Dx = __builtin_amdgcn_rcpf(fmaf(gy*gy, 0.25f, 1.f));
    float Dy = __builtin_amdgcn_rcpf(fmaf(gx*gx, 0.25f, 1.f));
    float ux = 0.5f * (gl - gr);
    float vy = 0.5f * (g1u - g1d);
    float Ax = gg*DTC, Ay = g11*DTC;
    float Bx = Dx*DTC, By = Dy*DTC;
    float Ev = (ux + vy)*DTC;
    float s2 = 2.f*(Bx + By);
    float Dv = __builtin_amdgcn_rcpf(1.f + s2);
    o0  = Dv*(1.f - s2);
    oE  = 2.f*Dv*Ev;
    omx = Dv*(2.f*Bx - Ax);
    opx = Dv*(2.f*Bx + Ax);
    omy = Dv*(2.f*By - Ay);
    opy = Dv*(2.f*By + Ay);
    oS  = Dv*(2.f*DTC)*fsrc;
}

template <typename T>
__global__ __launch_bounds__(NTH, 4)   // lb4: proven codegen; across-barrier live = 28 coef + hcr(4) = 32 VGPR
void diffusion_kernel(const T* __restrict__ s0,  const T* __restrict__ wg,  const T* __restrict__ wg1,
                      const T* __restrict__ g_gamma,  const T* __restrict__ g_beta,
                      const T* __restrict__ g_mean,   const T* __restrict__ g_var,
                      const T* __restrict__ g1_gamma, const T* __restrict__ g1_beta,
                      const T* __restrict__ g1_mean,  const T* __restrict__ g1_var,
                      const T* __restrict__ out_gamma, const T* __restrict__ out_beta,
                      const T* __restrict__ out_mean,  const T* __restrict__ out_var,
                      T* __restrict__ out,
                      const int* __restrict__ flag, int want)
{
    if (flag && *flag != want) return;   // dtype dispatch (dummy instance exits in ~9 us)

    __shared__ __hip_bfloat16 s0s[3][SJ][SW];      // 25728 B
    __shared__ float wgt[2][9][SJ];                //  2304 B
    __shared__ float bnp[4][SJ];                   //   512 B
    __shared__ float obn[2][16];                   //   128 B
    __shared__ __align__(16) float r2[2*28*HBS];   // 29568 B : gb/g1b (stride 128) then hA/hB (stride 132)
    // total 58240 B -> 2 blocks/CU (with VGPR<=32)

    const int tid = threadIdx.x;
    const int bid = blockIdx.x;
    const int h     = bid & 127;
    const int bc    = bid >> 7;
    const int chunk = bc & 15;
    const int b     = bc >> 4;
    const int c0    = chunk << 4;

    const int   rT   = (h > 0)   ? h - 1 : 1;      // sobel reflect rows
    const int   rB   = (h < 127) ? h + 1 : 126;
    const float topf = (h > 0)   ? 1.f : 0.f;      // conv zero-pad flags
    const float botf = (h < 127) ? 1.f : 0.f;

    // ---- stage s0: 3 rows x 32 ch x 128 w; 4-channel vector loads (3072 total, 3/thread) ----
    {
        const size_t base = (size_t)b * HN * WN * CN;
        #pragma unroll
        for (int k = 0; k < 3; ++k) {
            int e  = tid + k * NTH;                // < 3072
            int j4 = e & 7;                        // 4-channel group
            int w  = (e >> 3) & 127;
            int r  = e >> 10;                      // 0..2
            int row = (r == 0) ? rT : ((r == 1) ? h : rB);
            int cj  = (c0 - 8 + (j4 << 2)) & 255;  // 4-aligned group never straddles the wrap
            stage4(&s0s[r][j4 << 2][w + 1], &s0[base + ((size_t)row * WN + w) * CN + cj]);
        }
    }
    if (tid < 192) {                               // zero pad columns (conv SAME)
        int r = tid >> 6, j = (tid >> 1) & 31, cp = (tid & 1) ? 129 : 0;
        s0s[r][j][cp] = __float2bfloat16(0.f);
    }
    if (tid < 288) {                               // weights, H-pad folded in
        int t9 = tid >> 5, j = tid & 31;
        int cj = (c0 - 8 + j) & 255;
        float rf = (t9 < 3) ? topf : ((t9 >= 6) ? botf : 1.f);
        wgt[0][t9][j] = ldf(&wg [t9*CN + cj]) * rf;
        wgt[1][t9][j] = ldf(&wg1[t9*CN + cj]) * rf;
    }
    if (tid < 32) {                                // folded BN params
        int cj = (c0 - 8 + tid) & 255;
        float s  = ldf(&g_gamma[cj])  * rsqrtf(ldf(&g_var[cj])  + EPSV);
        bnp[0][tid] = s;
        bnp[1][tid] = ldf(&g_beta[cj])  - ldf(&g_mean[cj])  * s;
        float s1 = ldf(&g1_gamma[cj]) * rsqrtf(ldf(&g1_var[cj]) + EPSV);
        bnp[2][tid] = s1;
        bnp[3][tid] = ldf(&g1_beta[cj]) - ldf(&g1_mean[cj]) * s1;
    }
    if (tid < 16) {
        int c = c0 + tid;
        float s = ldf(&out_gamma[c]) * rsqrtf(ldf(&out_var[c]) + EPSV);
        obn[0][tid] = s;
        obn[1][tid] = ldf(&out_beta[c]) - ldf(&out_mean[c]) * s;
    }
    __syncthreads();   // B1

    float* gb  = r2;            // [28][128]
    float* g1b = r2 + 3584;

    // ---- pass 1: depthwise conv + BN + relu; aligned u32-pair LDS reads + unpack ----
    if (tid < 896) {            // 28 rows x 32 quads
        int wq = tid & 31, l = tid >> 5, j = l + 2, w0 = wq << 2;
        float col[3][6];
        #pragma unroll
        for (int r = 0; r < 3; ++r) {
            const unsigned* p = reinterpret_cast<const unsigned*>(&s0s[r][j][w0]);  // 4B-aligned
            unsigned d0 = p[0], d1 = p[1], d2 = p[2];
            col[r][0] = lo16(d0); col[r][1] = hi16(d0);
            col[r][2] = lo16(d1); col[r][3] = hi16(d1);
            col[r][4] = lo16(d2); col[r][5] = hi16(d2);
        }
        float gvk[4], g1vk[4];
        #pragma unroll
        for (int k = 0; k < 4; ++k) {
            float a = 0.f, a1 = 0.f;
            #pragma unroll
            for (int r = 0; r < 3; ++r)
                #pragma unroll
                for (int dx = 0; dx < 3; ++dx) {
                    float v = col[r][k + dx];
                    a  = fmaf(v, wgt[0][r*3+dx][j], a);
                    a1 = fmaf(v, wgt[1][r*3+dx][j], a1);
                }
            a  = fmaf(a,  bnp[0][j], bnp[1][j]);
            a1 = fmaf(a1, bnp[2][j], bnp[3][j]);
            gvk[k]  = fmaxf(a , 0.f);
            g1vk[k] = fmaxf(a1, 0.f);
        }
        *(float4*)&gb [l*128 + w0] = make_float4(gvk[0],  gvk[1],  gvk[2],  gvk[3]);
        *(float4*)&g1b[l*128 + w0] = make_float4(g1vk[0], g1vk[1], g1vk[2], g1vk[3]);
    }
    __syncthreads();   // B2

    // ---- thread geometry for pass 2 + Jacobi ----
    const int wq = tid & 31, ci = tid >> 5, w0 = wq << 2;  // ci in 0..25 for active
    const bool act = (tid < 832);                          // 26 rows x 32 quads (13 full waves)
    const int lane = tid & 63;
    const int sL = (lane & 32) | ((lane + 31) & 31);       // left rotate within half-wave (W wrap)
    const int sR = (lane & 32) | ((lane + 1)  & 31);

    // ---- pass 2: per-cell coefficients; scalar neighbor reads replaced by shuffles ----
    float4 ca0, caE, camx, capx, camy, capy, caS, fs;
    if (act) {
        int li = ci + 1, j = ci + 3;
        // phys cols w0..w0+5 = logical w0-1..w0+4 (the exact sobel window)
        float col[3][6];
        #pragma unroll
        for (int r = 0; r < 3; ++r) {
            const unsigned* p = reinterpret_cast<const unsigned*>(&s0s[r][j][w0]);
            unsigned d0 = p[0], d1 = p[1], d2 = p[2];
            col[r][0] = lo16(d0); col[r][1] = hi16(d0);
            col[r][2] = lo16(d1); col[r][3] = hi16(d1);
            col[r][4] = lo16(d2); col[r][5] = hi16(d2);
        }
        fs = make_float4(col[1][1], col[1][2], col[1][3], col[1][4]);
        // reflect overrides at W edges (pads hold conv zeros; sobel needs reflect)
        #pragma unroll
        for (int r = 0; r < 3; ++r) {
            col[r][0] = (wq == 0)  ? col[r][2] : col[r][0];
            col[r][5] = (wq == 31) ? col[r][3] : col[r][5];
        }
        float gX[6], dY[6];
        #pragma unroll
        for (int c = 0; c < 6; ++c) {
            gX[c] = col[0][c] + 2.f*col[1][c] + col[2][c];
            dY[c] = col[2][c] - col[0][c];
        }
        float4 gc  = *(float4*)&gb [li*128 + w0];
        float  gL  = __shfl(gc.w, sL);
        float  gR  = __shfl(gc.x, sR);
        float4 g1c = *(float4*)&g1b[li*128 + w0];
        float4 g1u = *(float4*)&g1b[(li-1)*128 + w0];
        float4 g1d = *(float4*)&g1b[(li+1)*128 + w0];

        #define GYV(K) (dY[K] + 2.f*dY[K+1] + dY[K+2])
        mkcoef(GYV(0), gX[2]-gX[0], gc.x, g1c.x, gL,   gc.y, g1u.x, g1d.x, fs.x,
               ca0.x, caE.x, camx.x, capx.x, camy.x, capy.x, caS.x);
        mkcoef(GYV(1), gX[3]-gX[1], gc.y, g1c.y, gc.x, gc.z, g1u.y, g1d.y, fs.y,
               ca0.y, caE.y, camx.y, capx.y, camy.y, capy.y, caS.y);
        mkcoef(GYV(2), gX[4]-gX[2], gc.z, g1c.z, gc.y, gc.w, g1u.z, g1d.z, fs.z,
               ca0.z, caE.z, camx.z, capx.z, camy.z, capy.z, caS.z);
        mkcoef(GYV(3), gX[5]-gX[3], gc.w, g1c.w, gc.z, gR,   g1u.w, g1d.w, fs.w,
               ca0.w, caE.w, camx.w, capx.w, camy.w, capy.w, caS.w);
        #undef GYV
    }
    __syncthreads();   // B3: gb/g1b reads done; r2 becomes hA/hB (stride HBS=132)

    // ---- Jacobi: hc carried in registers (own value); h0 from LDS own-address.
    //      Halo rows 0,27 never needed (5 iters propagate <=5 rows; outputs rows 6..21 see 1..26). ----
    float* hA = r2;              // [28][HBS]
    float* hB = r2 + 28*HBS;
    const int rb = ci*HBS + w0;  // row-above base; own row at rb+HBS

    auto JSTEP = [&](const float4& h0, const float4& hc, float eL, float eR,
                     const float4& up, const float4& dn) {
        float4 nw;
        nw.x = ca0.x*h0.x - caE.x*hc.x + camx.x*eL   + capx.x*hc.y + camy.x*up.x + capy.x*dn.x + caS.x;
        nw.y = ca0.y*h0.y - caE.y*hc.y + camx.y*hc.x + capx.y*hc.z + camy.y*up.y + capy.y*dn.y + caS.y;
        nw.z = ca0.z*h0.z - caE.z*hc.z + camx.z*hc.y + capx.z*hc.w + camy.z*up.z + capy.z*dn.z + caS.z;
        nw.w = ca0.w*h0.w - caE.w*hc.w + camx.w*hc.z + capx.w*eR   + camy.w*up.w + capy.w*dn.w + caS.w;
        return nw;
    };

    float4 hcr;   // h_{n} for the upcoming iter; born at iter 0

    // iter 0: operands all fsrc — from fs register + staged s0 mid-row for up/dn.
    //         Also park fs into hB own slot (becomes iter-1's h0 read) so fs dies here.
    if (act) {
        int j = ci + 3;
        const unsigned* pu = reinterpret_cast<const unsigned*>(&s0s[1][j-1][w0]);
        unsigned u0 = pu[0], u1 = pu[1], u2 = pu[2];
        float4 up0 = make_float4(hi16(u0), lo16(u1), hi16(u1), lo16(u2));
        const unsigned* pd = reinterpret_cast<const unsigned*>(&s0s[1][j+1][w0]);
        unsigned d0 = pd[0], d1 = pd[1], d2 = pd[2];
        float4 dn0 = make_float4(hi16(d0), lo16(d1), hi16(d1), lo16(d2));
        float eL0 = __shfl(fs.w, sL);
        float eR0 = __shfl(fs.x, sR);
        *(float4*)&hB[rb + HBS] = fs;                    // h0 slot for iter 1
        hcr = JSTEP(fs, fs, eL0, eR0, up0, dn0);         // h1
        *(float4*)&hA[rb + HBS] = hcr;                   // h1 -> hA (neighbors)
    }
    __syncthreads();   // B4

    // iter 1: cur=hA (h1); h0 = fs from hB own; write h2 -> hB
    if (act) {
        float4 up = *(float4*)&hA[rb];
        float4 dn = *(float4*)&hA[rb + 2*HBS];
        float4 h0 = *(float4*)&hB[rb + HBS];
        float eL = __shfl(hcr.w, sL);
        float eR = __shfl(hcr.x, sR);
        hcr = JSTEP(h0, hcr, eL, eR, up, dn);            // h2
        *(float4*)&hB[rb + HBS] = hcr;
    }
    __syncthreads();   // B5

    // iter 2: cur=hB (h2); h0 = h1 from hA own; write h3 -> hA
    if (act) {
        float4 up = *(float4*)&hB[rb];
        float4 dn = *(float4*)&hB[rb + 2*HBS];
        float4 h0 = *(float4*)&hA[rb + HBS];
        float eL = __shfl(hcr.w, sL);
        float eR = __shfl(hcr.x, sR);
        hcr = JSTEP(h0, hcr, eL, eR, up, dn);            // h3
        *(float4*)&hA[rb + HBS] = hcr;
    }
    __syncthreads();   // B6

    // iter 3: cur=hA (h3); h0 = h2 from hB own; write h4 -> hB
    if (act) {
        float4 up = *(float4*)&hA[rb];
        float4 dn = *(float4*)&hA[rb + 2*HBS];
        float4 h0 = *(float4*)&hB[rb + HBS];
        float eL = __shfl(hcr.w, sL);
        float eR = __shfl(hcr.x, sR);
        hcr = JSTEP(h0, hcr, eL, eR, up, dn);            // h4
        *(float4*)&hB[rb + HBS] = hcr;
    }
    __syncthreads();   // B7

    // iter 4: cur=hB (h4); h0 = h3 from hA own; write h5 -> hA (final)
    if (act) {
        float4 up = *(float4*)&hB[rb];
        float4 dn = *(float4*)&hB[rb + 2*HBS];
        float4 h0 = *(float4*)&hA[rb + HBS];
        float eL = __shfl(hcr.w, sL);
        float eR = __shfl(hcr.x, sR);
        hcr = JSTEP(h0, hcr, eL, eR, up, dn);            // h5
        *(float4*)&hA[rb + HBS] = hcr;
    }
    __syncthreads();   // B8

    // ---- pass 5: out = relu(bn(h)) on the 16 core channels (hA rows 6..21, stride 132 -> 2-way banks) ----
    if (tid < 512) {
        int i16 = tid & 15, w5 = ((tid >> 4) & 31) << 2;
        float4 v = *(float4*)&hA[(i16 + 6)*HBS + w5];
        float sc = obn[0][i16], bi = obn[1][i16];
        size_t ob = (((size_t)b*HN + h)*WN + w5)*CN + (c0 + i16);
        stf(&out[ob],          fmaxf(fmaf(v.x, sc, bi), 0.f));
        stf(&out[ob + CN],     fmaxf(fmaf(v.y, sc, bi), 0.f));
        stf(&out[ob + 2*CN],   fmaxf(fmaf(v.z, sc, bi), 0.f));
        stf(&out[ob + 3*CN],   fmaxf(fmaf(v.w, sc, bi), 0.f));
    }
}

extern "C" void kernel_launch(void* const* d_in, const int* in_sizes, int n_in,
                              void* d_out, int out_size, void* d_ws, size_t ws_size,
                              hipStream_t stream) {
    dim3 grid(BN * 16 * HN);   // 16384 blocks

    const long long nb    = (n_in > 0) ? (long long)in_sizes[0] : 0;
    const long long F32B  = (long long)BN * HN * WN * CN * 4;   // 134217728
    const long long BF16B = F32B / 2;                           //  67108864

    if (nb == F32B) {
        diffusion_kernel<float><<<grid, NTH, 0, stream>>>(
            (const float*)d_in[0], (const float*)d_in[1], (const float*)d_in[2],
            (const float*)d_in[3], (const float*)d_in[4], (const float*)d_in[5], (const float*)d_in[6],
            (const float*)d_in[7], (const float*)d_in[8], (const float*)d_in[9], (const float*)d_in[10],
            (const float*)d_in[11], (const float*)d_in[12], (const float*)d_in[13], (const float*)d_in[14],
            (float*)d_out, nullptr, 0);
    } else if (nb == BF16B) {
        diffusion_kernel<__hip_bfloat16><<<grid, NTH, 0, stream>>>(
            (const __hip_bfloat16*)d_in[0], (const __hip_bfloat16*)d_in[1], (const __hip_bfloat16*)d_in[2],
            (const __hip_bfloat16*)d_in[3], (const __hip_bfloat16*)d_in[4], (const __hip_bfloat16*)d_in[5], (const __hip_bfloat16*)d_in[6],
            (const __hip_bfloat16*)d_in[7], (const __hip_bfloat16*)d_in[8], (const __hip_bfloat16*)d_in[9], (const __hip_bfloat16*)d_in[10],
            (const __hip_bfloat16*)d_in[11], (const __hip_bfloat16*)d_in[12], (const __hip_bfloat16*)d_in[13], (const __hip_bfloat16*)d_in[14],
            (__hip_bfloat16*)d_out, nullptr, 0);
    } else if (ws_size >= 4) {
        int* flag = (int*)d_ws;
        probe_kernel<<<1, 256, 0, stream>>>((const unsigned int*)d_in[0], flag);

        diffusion_kernel<float><<<grid, NTH, 0, stream>>>(
            (const float*)d_in[0], (const float*)d_in[1], (const float*)d_in[2],
            (const float*)d_in[3], (const float*)d_in[4], (const float*)d_in[5], (const float*)d_in[6],
            (const float*)d_in[7], (const float*)d_in[8], (const float*)d_in[9], (const float*)d_in[10],
            (const float*)d_in[11], (const float*)d_in[12], (const float*)d_in[13], (const float*)d_in[14],
            (float*)d_out, flag, 0);

        diffusion_kernel<__hip_bfloat16><<<grid, NTH, 0, stream>>>(
            (const __hip_bfloat16*)d_in[0], (const __hip_bfloat16*)d_in[1], (const __hip_bfloat16*)d_in[2],
            (const __hip_bfloat16*)d_in[3], (const __hip_bfloat16*)d_in[4], (const __hip_bfloat16*)d_in[5], (const __hip_bfloat16*)d_in[6],
            (const __hip_bfloat16*)d_in[7], (const __hip_bfloat16*)d_in[8], (const __hip_bfloat16*)d_in[9], (const __hip_bfloat16*)d_in[10],
            (const __hip_bfloat16*)d_in[11], (const __hip_bfloat16*)d_in[12], (const __hip_bfloat16*)d_in[13], (const __hip_bfloat16*)d_in[14],
            (__hip_bfloat16*)d_out, flag, 1);
    } else {
        diffusion_kernel<float><<<grid, NTH, 0, stream>>>(
            (const float*)d_in[0], (const float*)d_in[1], (const float*)d_in[2],
            (const float*)d_in[3], (const float*)d_in[4], (const float*)d_in[5], (const float*)d_in[6],
            (const float*)d_in[7], (const float*)d_in[8], (const float*)d_in[9], (const float*)d_in[10],
            (const float*)d_in[11], (const float*)d_in[12], (const float*)d_in[13], (const float*)d_in[14],
            (float*)d_out, nullptr, 0);
    }
}

// Round 11
// 481.902 us; speedup vs baseline: 1.0127x; 1.0127x over previous
//
#include <hip/hip_runtime.h>
#include <hip/hip_bf16.h>

#define BN 8
#define HN 128
#define WN 128
#define CN 256
#define DTC 0.2f
#define EPSV 1e-3f
#define NTH 1024

#define SJ 32      // staged channel rows (phys j: cj = c0-8+j)
#define SW 134     // w stride (u16): col0 & col129 zero pads, data at 1..128; rows 4B-aligned
#define HBS 132    // h-buffer row stride (floats): ≡4 mod 32 banks -> pass-5 column reads 2-way (free)

// ---- dtype-generic helpers (compute stays f32) ----
__device__ __forceinline__ float ldf(const float* p)            { return *p; }
__device__ __forceinline__ float ldf(const __hip_bfloat16* p)   { return __bfloat162float(*p); }
__device__ __forceinline__ void stf(float* p, float v)          { *p = v; }
__device__ __forceinline__ void stf(__hip_bfloat16* p, float v) { *p = __float2bfloat16(v); }

// packed bf16 extraction from u32 (exact f32), little-endian: lo = even col
__device__ __forceinline__ float lo16(unsigned u){ return __uint_as_float(u << 16); }
__device__ __forceinline__ float hi16(unsigned u){ return __uint_as_float(u & 0xffff0000u); }

// stage 4 consecutive channels (one vector global load) into 4 LDS channel-rows
__device__ __forceinline__ void stage4(__hip_bfloat16* dp, const __hip_bfloat16* gp) {
    ushort4 v = *reinterpret_cast<const ushort4*>(gp);
    unsigned short* d = reinterpret_cast<unsigned short*>(dp);
    d[0] = v.x; d[SW] = v.y; d[2*SW] = v.z; d[3*SW] = v.w;
}
__device__ __forceinline__ void stage4(__hip_bfloat16* dp, const float* gp) {
    float4 v = *reinterpret_cast<const float4*>(gp);
    dp[0]    = __float2bfloat16(v.x);
    dp[SW]   = __float2bfloat16(v.y);
    dp[2*SW] = __float2bfloat16(v.z);
    dp[3*SW] = __float2bfloat16(v.w);
}

// ---- dtype probe: bf16 exponent band test on raw u32 words ----
__global__ void probe_kernel(const unsigned int* __restrict__ s0w, int* __restrict__ flag) {
    __shared__ int cnt;
    if (threadIdx.x == 0) cnt = 0;
    __syncthreads();
    int local = 0;
    for (int i = threadIdx.x; i < 4096; i += 256) {
        unsigned int e = (s0w[i] >> 7) & 0xFF;
        if (e >= 118 && e <= 130) local++;
    }
    atomicAdd(&cnt, local);
    __syncthreads();
    if (threadIdx.x == 0) *flag = (cnt > 2048) ? 1 : 0;   // 1 = bf16, 0 = f32
}

__device__ __forceinline__ void mkcoef(float gy, float gx, float gg, float g11,
                                       float gl, float gr, float g1u, float g1d, float fsrc,
                                       float& o0, float& oE, float& omx, float& opx,
                                       float& omy, float& opy, float& oS)
{
    // v_rcp_f32 (1 ulp) — tolerance 0.0625; validated r2-r4/r7/r8.
    float Dx = __builtin_amdgcn_rcpf(fmaf(gy*gy, 0.25f, 1.f));
    float Dy = __builtin_amdgcn_rcpf(fmaf(gx*gx, 0.25f, 1.f));
    float ux = 0.5f * (gl - gr);
    float vy = 0.5f * (g1u - g1d);
    float Ax = gg*DTC, Ay = g11*DTC;
    float Bx = Dx*DTC, By = Dy*DTC;
    float Ev = (ux + vy)*DTC;
    float s2 = 2.f*(Bx + By);
    float Dv = __builtin_amdgcn_rcpf(1.f + s2);
    o0  = Dv*(1.f - s2);
    oE  = 2.f*Dv*Ev;
    omx = Dv*(2.f*Bx - Ax);
    opx = Dv*(2.f*Bx + Ax);
    omy = Dv*(2.f*By - Ay);
    opy = Dv*(2.f*By + Ay);
    oS  = Dv*(2.f*DTC)*fsrc;
}

template <typename T>
__global__ __launch_bounds__(NTH, 4)   // lb4: proven codegen; r8 Jacobi structure (no hcr chain — r10 regression)
void diffusion_kernel(const T* __restrict__ s0,  const T* __restrict__ wg,  const T* __restrict__ wg1,
                      const T* __restrict__ g_gamma,  const T* __restrict__ g_beta,
                      const T* __restrict__ g_mean,   const T* __restrict__ g_var,
                      const T* __restrict__ g1_gamma, const T* __restrict__ g1_beta,
                      const T* __restrict__ g1_mean,  const T* __restrict__ g1_var,
                      const T* __restrict__ out_gamma, const T* __restrict__ out_beta,
                      const T* __restrict__ out_mean,  const T* __restrict__ out_var,
                      T* __restrict__ out,
                      const int* __restrict__ flag, int want)
{
    if (flag && *flag != want) return;   // dtype dispatch (dummy instance exits in ~9 us)

    __shared__ __hip_bfloat16 s0s[3][SJ][SW];      // 25728 B
    __shared__ float wgt[2][9][SJ];                //  2304 B
    __shared__ float bnp[4][SJ];                   //   512 B
    __shared__ float obn[2][16];                   //   128 B
    __shared__ __align__(16) float r2[2*28*HBS];   // 29568 B : gb/g1b (stride 128) then hA/hB (stride 132)
    // total 58240 B -> 2 blocks/CU (with VGPR<=32)

    const int tid = threadIdx.x;
    const int bid = blockIdx.x;
    const int h     = bid & 127;
    const int bc    = bid >> 7;
    const int chunk = bc & 15;
    const int b     = bc >> 4;
    const int c0    = chunk << 4;

    const int   rT   = (h > 0)   ? h - 1 : 1;      // sobel reflect rows
    const int   rB   = (h < 127) ? h + 1 : 126;
    const float topf = (h > 0)   ? 1.f : 0.f;      // conv zero-pad flags
    const float botf = (h < 127) ? 1.f : 0.f;

    // ---- stage s0: 3 rows x 32 ch x 128 w; 4-channel vector loads (3072 total, 3/thread) ----
    {
        const size_t base = (size_t)b * HN * WN * CN;
        #pragma unroll
        for (int k = 0; k < 3; ++k) {
            int e  = tid + k * NTH;                // < 3072
            int j4 = e & 7;                        // 4-channel group
            int w  = (e >> 3) & 127;
            int r  = e >> 10;                      // 0..2
            int row = (r == 0) ? rT : ((r == 1) ? h : rB);
            int cj  = (c0 - 8 + (j4 << 2)) & 255;  // 4-aligned group never straddles the wrap
            stage4(&s0s[r][j4 << 2][w + 1], &s0[base + ((size_t)row * WN + w) * CN + cj]);
        }
    }
    if (tid < 192) {                               // zero pad columns (conv SAME)
        int r = tid >> 6, j = (tid >> 1) & 31, cp = (tid & 1) ? 129 : 0;
        s0s[r][j][cp] = __float2bfloat16(0.f);
    }
    if (tid < 288) {                               // weights, H-pad folded in
        int t9 = tid >> 5, j = tid & 31;
        int cj = (c0 - 8 + j) & 255;
        float rf = (t9 < 3) ? topf : ((t9 >= 6) ? botf : 1.f);
        wgt[0][t9][j] = ldf(&wg [t9*CN + cj]) * rf;
        wgt[1][t9][j] = ldf(&wg1[t9*CN + cj]) * rf;
    }
    if (tid < 32) {                                // folded BN params
        int cj = (c0 - 8 + tid) & 255;
        float s  = ldf(&g_gamma[cj])  * rsqrtf(ldf(&g_var[cj])  + EPSV);
        bnp[0][tid] = s;
        bnp[1][tid] = ldf(&g_beta[cj])  - ldf(&g_mean[cj])  * s;
        float s1 = ldf(&g1_gamma[cj]) * rsqrtf(ldf(&g1_var[cj]) + EPSV);
        bnp[2][tid] = s1;
        bnp[3][tid] = ldf(&g1_beta[cj]) - ldf(&g1_mean[cj]) * s1;
    }
    if (tid < 16) {
        int c = c0 + tid;
        float s = ldf(&out_gamma[c]) * rsqrtf(ldf(&out_var[c]) + EPSV);
        obn[0][tid] = s;
        obn[1][tid] = ldf(&out_beta[c]) - ldf(&out_mean[c]) * s;
    }
    __syncthreads();   // B1

    float* gb  = r2;            // [28][128]
    float* g1b = r2 + 3584;

    // ---- pass 1: depthwise conv + BN + relu; aligned u32-pair LDS reads + unpack ----
    if (tid < 896) {            // 28 rows x 32 quads
        int wq = tid & 31, l = tid >> 5, j = l + 2, w0 = wq << 2;
        float col[3][6];
        #pragma unroll
        for (int r = 0; r < 3; ++r) {
            const unsigned* p = reinterpret_cast<const unsigned*>(&s0s[r][j][w0]);  // 4B-aligned
            unsigned d0 = p[0], d1 = p[1], d2 = p[2];
            col[r][0] = lo16(d0); col[r][1] = hi16(d0);
            col[r][2] = lo16(d1); col[r][3] = hi16(d1);
            col[r][4] = lo16(d2); col[r][5] = hi16(d2);
        }
        float gvk[4], g1vk[4];
        #pragma unroll
        for (int k = 0; k < 4; ++k) {
            float a = 0.f, a1 = 0.f;
            #pragma unroll
            for (int r = 0; r < 3; ++r)
                #pragma unroll
                for (int dx = 0; dx < 3; ++dx) {
                    float v = col[r][k + dx];
                    a  = fmaf(v, wgt[0][r*3+dx][j], a);
                    a1 = fmaf(v, wgt[1][r*3+dx][j], a1);
                }
            a  = fmaf(a,  bnp[0][j], bnp[1][j]);
            a1 = fmaf(a1, bnp[2][j], bnp[3][j]);
            gvk[k]  = fmaxf(a , 0.f);
            g1vk[k] = fmaxf(a1, 0.f);
        }
        *(float4*)&gb [l*128 + w0] = make_float4(gvk[0],  gvk[1],  gvk[2],  gvk[3]);
        *(float4*)&g1b[l*128 + w0] = make_float4(g1vk[0], g1vk[1], g1vk[2], g1vk[3]);
    }
    __syncthreads();   // B2

    // ---- thread geometry for pass 2 + Jacobi ----
    const int wq = tid & 31, ci = tid >> 5, w0 = wq << 2;  // ci in 0..25 for active
    const bool act = (tid < 832);                          // 26 rows x 32 quads (13 full waves)
    const int lane = tid & 63;
    const int sL = (lane & 32) | ((lane + 31) & 31);       // left rotate within half-wave (W wrap)
    const int sR = (lane & 32) | ((lane + 1)  & 31);

    // ---- pass 2: per-cell coefficients; scalar neighbor reads replaced by shuffles ----
    float4 ca0, caE, camx, capx, camy, capy, caS, fs;
    if (act) {
        int li = ci + 1, j = ci + 3;
        // phys cols w0..w0+5 = logical w0-1..w0+4 (the exact sobel window)
        float col[3][6];
        #pragma unroll
        for (int r = 0; r < 3; ++r) {
            const unsigned* p = reinterpret_cast<const unsigned*>(&s0s[r][j][w0]);
            unsigned d0 = p[0], d1 = p[1], d2 = p[2];
            col[r][0] = lo16(d0); col[r][1] = hi16(d0);
            col[r][2] = lo16(d1); col[r][3] = hi16(d1);
            col[r][4] = lo16(d2); col[r][5] = hi16(d2);
        }
        fs = make_float4(col[1][1], col[1][2], col[1][3], col[1][4]);
        // reflect overrides at W edges (pads hold conv zeros; sobel needs reflect)
        #pragma unroll
        for (int r = 0; r < 3; ++r) {
            col[r][0] = (wq == 0)  ? col[r][2] : col[r][0];
            col[r][5] = (wq == 31) ? col[r][3] : col[r][5];
        }
        float gX[6], dY[6];
        #pragma unroll
        for (int c = 0; c < 6; ++c) {
            gX[c] = col[0][c] + 2.f*col[1][c] + col[2][c];
            dY[c] = col[2][c] - col[0][c];
        }
        float4 gc  = *(float4*)&gb [li*128 + w0];
        float  gL  = __shfl(gc.w, sL);
        float  gR  = __shfl(gc.x, sR);
        float4 g1c = *(float4*)&g1b[li*128 + w0];
        float4 g1u = *(float4*)&g1b[(li-1)*128 + w0];
        float4 g1d = *(float4*)&g1b[(li+1)*128 + w0];

        #define GYV(K) (dY[K] + 2.f*dY[K+1] + dY[K+2])
        mkcoef(GYV(0), gX[2]-gX[0], gc.x, g1c.x, gL,   gc.y, g1u.x, g1d.x, fs.x,
               ca0.x, caE.x, camx.x, capx.x, camy.x, capy.x, caS.x);
        mkcoef(GYV(1), gX[3]-gX[1], gc.y, g1c.y, gc.x, gc.z, g1u.y, g1d.y, fs.y,
               ca0.y, caE.y, camx.y, capx.y, camy.y, capy.y, caS.y);
        mkcoef(GYV(2), gX[4]-gX[2], gc.z, g1c.z, gc.y, gc.w, g1u.z, g1d.z, fs.z,
               ca0.z, caE.z, camx.z, capx.z, camy.z, capy.z, caS.z);
        mkcoef(GYV(3), gX[5]-gX[3], gc.w, g1c.w, gc.z, gR,   g1u.w, g1d.w, fs.w,
               ca0.w, caE.w, camx.w, capx.w, camy.w, capy.w, caS.w);
        #undef GYV
    }
    __syncthreads();   // B3: gb/g1b reads done; r2 becomes hA/hB (stride HBS=132)

    // ---- Jacobi (r8 structure): hc read from LDS; fs live through iter 1.
    //      Halo rows 0,27 never needed (5 iters propagate <=5 rows; outputs rows 6..21 see 1..26). ----
    float* hA = r2;              // [28][HBS]
    float* hB = r2 + 28*HBS;
    const int rb = ci*HBS + w0;  // row-above base; own row at rb+HBS

    auto JSTEP = [&](const float4& h0, const float4& hc, float eL, float eR,
                     const float4& up, const float4& dn) {
        float4 nw;
        nw.x = ca0.x*h0.x - caE.x*hc.x + camx.x*eL   + capx.x*hc.y + camy.x*up.x + capy.x*dn.x + caS.x;
        nw.y = ca0.y*h0.y - caE.y*hc.y + camx.y*hc.x + capx.y*hc.z + camy.y*up.y + capy.y*dn.y + caS.y;
        nw.z = ca0.z*h0.z - caE.z*hc.z + camx.z*hc.y + capx.z*hc.w + camy.z*up.z + capy.z*dn.z + caS.z;
        nw.w = ca0.w*h0.w - caE.w*hc.w + camx.w*hc.z + capx.w*eR   + camy.w*up.w + capy.w*dn.w + caS.w;
        return nw;
    };

    // iter 0: all operands fsrc — from fs register + staged s0 mid-row for up/dn.
    if (act) {
        int j = ci + 3;
        const unsigned* pu = reinterpret_cast<const unsigned*>(&s0s[1][j-1][w0]);
        unsigned u0 = pu[0], u1 = pu[1], u2 = pu[2];
        float4 up0 = make_float4(hi16(u0), lo16(u1), hi16(u1), lo16(u2));
        const unsigned* pd = reinterpret_cast<const unsigned*>(&s0s[1][j+1][w0]);
        unsigned d0 = pd[0], d1 = pd[1], d2 = pd[2];
        float4 dn0 = make_float4(hi16(d0), lo16(d1), hi16(d1), lo16(d2));
        float eL0 = __shfl(fs.w, sL);
        float eR0 = __shfl(fs.x, sR);
        float4 nw = JSTEP(fs, fs, eL0, eR0, up0, dn0);   // h1
        *(float4*)&hA[rb + HBS] = nw;                    // h1 -> hA
    }
    __syncthreads();   // B4

    // iter 1: cur=hA (h1); h0 = fs (register); write h2 -> hB
    if (act) {
        float4 up = *(float4*)&hA[rb];
        float4 hc = *(float4*)&hA[rb + HBS];
        float4 dn = *(float4*)&hA[rb + 2*HBS];
        float eL = __shfl(hc.w, sL);
        float eR = __shfl(hc.x, sR);
        float4 nw = JSTEP(fs, hc, eL, eR, up, dn);       // h2
        *(float4*)&hB[rb + HBS] = nw;
    }
    __syncthreads();   // B5

    // iter 2: cur=hB (h2); h0 = h1 from hA own (thread-private RMW); write h3 -> hA
    if (act) {
        float4 up = *(float4*)&hB[rb];
        float4 hc = *(float4*)&hB[rb + HBS];
        float4 dn = *(float4*)&hB[rb + 2*HBS];
        float4 h0 = *(float4*)&hA[rb + HBS];
        float eL = __shfl(hc.w, sL);
        float eR = __shfl(hc.x, sR);
        float4 nw = JSTEP(h0, hc, eL, eR, up, dn);       // h3
        *(float4*)&hA[rb + HBS] = nw;
    }
    __syncthreads();   // B6

    // iter 3: cur=hA (h3); h0 = h2 from hB own; write h4 -> hB
    if (act) {
        float4 up = *(float4*)&hA[rb];
        float4 hc = *(float4*)&hA[rb + HBS];
        float4 dn = *(float4*)&hA[rb + 2*HBS];
        float4 h0 = *(float4*)&hB[rb + HBS];
        float eL = __shfl(hc.w, sL);
        float eR = __shfl(hc.x, sR);
        float4 nw = JSTEP(h0, hc, eL, eR, up, dn);       // h4
        *(float4*)&hB[rb + HBS] = nw;
    }
    __syncthreads();   // B7

    // iter 4: cur=hB (h4); h0 = h3 from hA own; write h5 -> hA (final)
    if (act) {
        float4 up = *(float4*)&hB[rb];
        float4 hc = *(float4*)&hB[rb + HBS];
        float4 dn = *(float4*)&hB[rb + 2*HBS];
        float4 h0 = *(float4*)&hA[rb + HBS];
        float eL = __shfl(hc.w, sL);
        float eR = __shfl(hc.x, sR);
        float4 nw = JSTEP(h0, hc, eL, eR, up, dn);       // h5
        *(float4*)&hA[rb + HBS] = nw;
    }
    __syncthreads();   // B8

    // ---- pass 5: out = relu(bn(h)) on the 16 core channels (hA rows 6..21, stride 132 -> 2-way banks) ----
    if (tid < 512) {
        int i16 = tid & 15, w5 = ((tid >> 4) & 31) << 2;
        float4 v = *(float4*)&hA[(i16 + 6)*HBS + w5];
        float sc = obn[0][i16], bi = obn[1][i16];
        size_t ob = (((size_t)b*HN + h)*WN + w5)*CN + (c0 + i16);
        stf(&out[ob],          fmaxf(fmaf(v.x, sc, bi), 0.f));
        stf(&out[ob + CN],     fmaxf(fmaf(v.y, sc, bi), 0.f));
        stf(&out[ob + 2*CN],   fmaxf(fmaf(v.z, sc, bi), 0.f));
        stf(&out[ob + 3*CN],   fmaxf(fmaf(v.w, sc, bi), 0.f));
    }
}

extern "C" void kernel_launch(void* const* d_in, const int* in_sizes, int n_in,
                              void* d_out, int out_size, void* d_ws, size_t ws_size,
                              hipStream_t stream) {
    dim3 grid(BN * 16 * HN);   // 16384 blocks

    const long long nb    = (n_in > 0) ? (long long)in_sizes[0] : 0;
    const long long F32B  = (long long)BN * HN * WN * CN * 4;   // 134217728
    const long long BF16B = F32B / 2;                           //  67108864

    if (nb == F32B) {
        diffusion_kernel<float><<<grid, NTH, 0, stream>>>(
            (const float*)d_in[0], (const float*)d_in[1], (const float*)d_in[2],
            (const float*)d_in[3], (const float*)d_in[4], (const float*)d_in[5], (const float*)d_in[6],
            (const float*)d_in[7], (const float*)d_in[8], (const float*)d_in[9], (const float*)d_in[10],
            (const float*)d_in[11], (const float*)d_in[12], (const float*)d_in[13], (const float*)d_in[14],
            (float*)d_out, nullptr, 0);
    } else if (nb == BF16B) {
        diffusion_kernel<__hip_bfloat16><<<grid, NTH, 0, stream>>>(
            (const __hip_bfloat16*)d_in[0], (const __hip_bfloat16*)d_in[1], (const __hip_bfloat16*)d_in[2],
            (const __hip_bfloat16*)d_in[3], (const __hip_bfloat16*)d_in[4], (const __hip_bfloat16*)d_in[5], (const __hip_bfloat16*)d_in[6],
            (const __hip_bfloat16*)d_in[7], (const __hip_bfloat16*)d_in[8], (const __hip_bfloat16*)d_in[9], (const __hip_bfloat16*)d_in[10],
            (const __hip_bfloat16*)d_in[11], (const __hip_bfloat16*)d_in[12], (const __hip_bfloat16*)d_in[13], (const __hip_bfloat16*)d_in[14],
            (__hip_bfloat16*)d_out, nullptr, 0);
    } else if (ws_size >= 4) {
        int* flag = (int*)d_ws;
        probe_kernel<<<1, 256, 0, stream>>>((const unsigned int*)d_in[0], flag);

        diffusion_kernel<float><<<grid, NTH, 0, stream>>>(
            (const float*)d_in[0], (const float*)d_in[1], (const float*)d_in[2],
            (const float*)d_in[3], (const float*)d_in[4], (const float*)d_in[5], (const float*)d_in[6],
            (const float*)d_in[7], (const float*)d_in[8], (const float*)d_in[9], (const float*)d_in[10],
            (const float*)d_in[11], (const float*)d_in[12], (const float*)d_in[13], (const float*)d_in[14],
            (float*)d_out, flag, 0);

        diffusion_kernel<__hip_bfloat16><<<grid, NTH, 0, stream>>>(
            (const __hip_bfloat16*)d_in[0], (const __hip_bfloat16*)d_in[1], (const __hip_bfloat16*)d_in[2],
            (const __hip_bfloat16*)d_in[3], (const __hip_bfloat16*)d_in[4], (const __hip_bfloat16*)d_in[5], (const __hip_bfloat16*)d_in[6],
            (const __hip_bfloat16*)d_in[7], (const __hip_bfloat16*)d_in[8], (const __hip_bfloat16*)d_in[9], (const __hip_bfloat16*)d_in[10],
            (const __hip_bfloat16*)d_in[11], (const __hip_bfloat16*)d_in[12], (const __hip_bfloat16*)d_in[13], (const __hip_bfloat16*)d_in[14],
            (__hip_bfloat16*)d_out, flag, 1);
    } else {
        diffusion_kernel<float><<<grid, NTH, 0, stream>>>(
            (const float*)d_in[0], (const float*)d_in[1], (const float*)d_in[2],
            (const float*)d_in[3], (const float*)d_in[4], (const float*)d_in[5], (const float*)d_in[6],
            (const float*)d_in[7], (const float*)d_in[8], (const float*)d_in[9], (const float*)d_in[10],
            (const float*)d_in[11], (const float*)d_in[12], (const float*)d_in[13], (const float*)d_in[14],
            (float*)d_out, nullptr, 0);
    }
}